// Round 6
// baseline (987.830 us; speedup 1.0000x reference)
//
#include <hip/hip_runtime.h>
#include <hip/hip_bf16.h>
#include <hip/hip_cooperative_groups.h>
#include <cstdint>
#include <cstddef>

// minLSTM: out = exp(heinsen_scan(log_f, log_i + log_g(h))), [h,f,i] = x @ W
// B=4 S=8192 D=1024. GEMM bf16 MFMA (fp32 accum) -> bf16 hW; linear-domain
// chunked EMA scan (F=sigmoid(-d), I=1-F) with log-domain cross-chunk scan.
// R10: scans fused into ONE cooperative kernel (phase1 -> grid.sync ->
// phase2 -> grid.sync -> phase3). agg/pre re-laid out [chunk][channel] so
// the large streams are coalesced; the transposed access moves to the 8MB
// L3-resident phase 2. Fallback to 3 separate kernels if cooperative launch
// is unsupported. GEMM: R8 2-barrier schedule, unchanged.

namespace cg = cooperative_groups;

#define BB 4
#define SS 8192
#define DD 1024
#define MM 32768   // B*S
#define KK 1024    // D
#define NN 3072    // 3*D
#define CHUNKS 256
#define CLEN 32    // SS / CHUNKS
#define NCH 4096   // B*D channels
#define NT 16      // KK / 64 K-tiles

typedef __bf16 bf16;
typedef __bf16 bf16x2 __attribute__((ext_vector_type(2)));
typedef __bf16 bf16x4 __attribute__((ext_vector_type(4)));
typedef __bf16 bf16x8 __attribute__((ext_vector_type(8)));
typedef float f32x4 __attribute__((ext_vector_type(4)));

// ---- async global->LDS, 16B per lane (wave-uniform LDS base + lane*16) ----
__device__ __forceinline__ void gload16(const bf16* g, bf16* l) {
  __builtin_amdgcn_global_load_lds(
      (const __attribute__((address_space(1))) unsigned int*)(const void*)g,
      (__attribute__((address_space(3))) unsigned int*)(void*)l,
      16, 0, 0);
}

// ---- native 2^x (hedged: fall back to __expf if builtin name is absent) ---
#if __has_builtin(__builtin_amdgcn_exp2f)
#define EXP2(x) __builtin_amdgcn_exp2f(x)
#else
#define EXP2(x) __expf((x) * 0.69314718056f)
#endif

// ---- agent-scope 8B load (cross-XCD coherent read after grid sync) --------
__device__ __forceinline__ float2 aload(const float2* p) {
  unsigned long long u = __hip_atomic_load(
      (const unsigned long long*)p, __ATOMIC_RELAXED, __HIP_MEMORY_SCOPE_AGENT);
  union { unsigned long long u; float2 f; } c;
  c.u = u;
  return c.f;
}

// ---- linear-domain gate evaluation (base-2) -------------------------------
// F = sigmoid(-(sp(-f)-sp(-i))) = (1+e^-i)/(2+e^-f+e^-i); I = 1-F.
// IG = I * g(h), g(h) = h>=0 ? h+0.5 : sigmoid(h).
// Clamp exp2 args at 60: P<=2^60 keeps rZ normal; IG -> (P)(gh)(1/P) = gh ok.
__device__ __forceinline__ void gate2(float h, float f, float i,
                                      float& F, float& IG) {
  const float NL2E = -1.44269504089f;  // -log2(e)
  float P = EXP2(fminf(f * NL2E, 60.f));
  float Q = EXP2(fminf(i * NL2E, 60.f));
  float H = EXP2(fminf(h * NL2E, 60.f));
  float rZ = __builtin_amdgcn_rcpf(2.f + P + Q);
  float gh = (h >= 0.f) ? (h + 0.5f) : __builtin_amdgcn_rcpf(1.f + H);
  F = (1.f + Q) * rZ;
  IG = (1.f + P) * gh * rZ;
}

// ---- log-domain combine for the cross-chunk scan --------------------------
__device__ __forceinline__ float laddexp(float a, float b) {
  float m = fmaxf(a, b);
  return m + __logf(1.f + __expf(fminf(a, b) - m));
}
__device__ __forceinline__ void comb(float& A, float& V, float Ac, float Vc) {
  V = laddexp(V + Ac, Vc);
  A += Ac;
}

// ---- convert x fp32 -> bf16 (vectorized) ----
__global__ __launch_bounds__(256) void k_cvt_x(const float4* __restrict__ x,
                                               bf16x4* __restrict__ xb) {
  int i = blockIdx.x * 256 + threadIdx.x;
  float4 v = x[i];
  bf16x4 o;
  o[0] = (bf16)v.x; o[1] = (bf16)v.y; o[2] = (bf16)v.z; o[3] = (bf16)v.w;
  xb[i] = o;
}

// ---- convert + transpose W [K,N] fp32 -> Wt [N,K] bf16 (LDS 32x32 tile) ----
__global__ __launch_bounds__(256) void k_cvt_wt(const float* __restrict__ W,
                                                bf16* __restrict__ Wt) {
  __shared__ float tile[32][33];
  int n0 = blockIdx.x * 32, k0 = blockIdx.y * 32;
  int tx = threadIdx.x, ty = threadIdx.y;  // (32, 8)
#pragma unroll
  for (int i = 0; i < 32; i += 8)
    tile[ty + i][tx] = W[(size_t)(k0 + ty + i) * NN + n0 + tx];
  __syncthreads();
#pragma unroll
  for (int i = 0; i < 32; i += 8)
    Wt[(size_t)(n0 + ty + i) * KK + k0 + tx] = (bf16)tile[tx][ty + i];
}

// ---- bf16 GEMM, C[m][n] = sum_k A[m][k]*Bt[n][k] --------------------------
// 256x256 tile, BK=64, 8 waves (2Mx4N), counted vmcnt, LDS XOR-swizzle,
// dual B-frag sets, 2 barriers per K-tile. (R8, unchanged)
__global__ __launch_bounds__(512, 2) void k_gemm(const bf16* __restrict__ A,
                                                 const bf16* __restrict__ Bt,
                                                 bf16* __restrict__ C) {
  __shared__ __align__(16) bf16 sm[65536];  // 128 KiB
  const int tid = threadIdx.x;
  const int lane = tid & 63;
  const int w = tid >> 6;          // 0..7
  const int wm = w >> 2;           // 0..1 (M)
  const int wn = w & 3;            // 0..3 (N)
  const int c16 = lane & 15;
  const int l4 = lane >> 4;

  // XCD-aware bijective swizzle: 1536 blocks = 8 XCD * 192; nT fast inside
  // a chunk so consecutive same-XCD blocks reuse the A panel in L2.
  int bid = blockIdx.x;
  int swz = (bid & 7) * 192 + (bid >> 3);
  int mT = swz / 12;
  int nT = swz - mT * 12;
  const int mBase = mT * 256, nBase = nT * 256;

  // staging: thread covers LDS linear slot (row = tid>>3 (+64*L +128*half),
  // slot = tid&7); global source column pre-swizzled (inverse of read XOR).
  const int sr = tid >> 3;                       // 0..63
  const int scol = ((tid & 7) ^ (sr & 7)) * 8;   // swizzled k-col (elems)
  const bf16* gA = A + (size_t)(mBase + sr) * KK + scol;
  const bf16* gB = Bt + (size_t)(nBase + sr) * KK + scol;
  const int ld = tid * 8;                        // linear LDS dest (elems)

  // ds_read: addr = region + row*64 + ((slot ^ (row&7))*8); row&7 == c16&7
  const int sw8 = c16 & 7;
  const int sx0 = (l4 ^ sw8) * 8;          // ksub=0 (slots 0..3)
  const int sx1 = ((l4 + 4) ^ sw8) * 8;    // ksub=1 (slots 4..7)
  const int aRow = (wm * 64 + c16) * 64;   // + qm*8192 + mi*1024
  const int bRow = (wn * 32 + c16) * 64;   // + qn*8192 + ni*1024

  f32x4 acc[2][2][4][2];  // [qm][qn][mi][ni]
#pragma unroll
  for (int a = 0; a < 2; ++a)
#pragma unroll
    for (int b2 = 0; b2 < 2; ++b2)
#pragma unroll
      for (int m = 0; m < 4; ++m)
#pragma unroll
        for (int n = 0; n < 2; ++n)
          acc[a][b2][m][n] = (f32x4){0.f, 0.f, 0.f, 0.f};

#define STGA(h, L, bo, ko) \
  gload16(gA + (h) * 131072 + (L) * 65536 + (ko), \
          sm + (bo) + (h) * 8192 + (L) * 4096 + ld)
#define STGB(h, L, bo, ko) \
  gload16(gB + (h) * 131072 + (L) * 65536 + (ko), \
          sm + (bo) + 16384 + (h) * 8192 + (L) * 4096 + ld)
#define LDA(qm, AF)                                                     \
  _Pragma("unroll") for (int mi = 0; mi < 4; ++mi) {                    \
    const bf16* p_ = sm + buf + (qm) * 8192 + aRow + mi * 1024;         \
    AF[mi][0] = *(const bf16x8*)(p_ + sx0);                             \
    AF[mi][1] = *(const bf16x8*)(p_ + sx1);                             \
  }
#define LDB(qn, BF)                                                     \
  _Pragma("unroll") for (int ni = 0; ni < 2; ++ni) {                    \
    const bf16* p_ = sm + buf + 16384 + (qn) * 8192 + bRow + ni * 1024; \
    BF[ni][0] = *(const bf16x8*)(p_ + sx0);                             \
    BF[ni][1] = *(const bf16x8*)(p_ + sx1);                             \
  }
#define MFMAQ(qm, qn, AF, BF)                                             \
  __builtin_amdgcn_s_setprio(1);                                          \
  _Pragma("unroll") for (int mi = 0; mi < 4; ++mi)                        \
  _Pragma("unroll") for (int ni = 0; ni < 2; ++ni) {                      \
    acc[qm][qn][mi][ni] = __builtin_amdgcn_mfma_f32_16x16x32_bf16(        \
        AF[mi][0], BF[ni][0], acc[qm][qn][mi][ni], 0, 0, 0);              \
    acc[qm][qn][mi][ni] = __builtin_amdgcn_mfma_f32_16x16x32_bf16(        \
        AF[mi][1], BF[ni][1], acc[qm][qn][mi][ni], 0, 0, 0);              \
  }                                                                       \
  __builtin_amdgcn_s_setprio(0);
#define BAR asm volatile("s_barrier" ::: "memory")
#define VMC(n) asm volatile("s_waitcnt vmcnt(" #n ")" ::: "memory")

  // prologue: stage K-tile 0 into buffer 0 (issue order A0,B0,A1,B1)
  STGA(0, 0, 0, 0); STGA(0, 1, 0, 0); STGB(0, 0, 0, 0); STGB(0, 1, 0, 0);
  STGA(1, 0, 0, 0); STGA(1, 1, 0, 0); STGB(1, 0, 0, 0); STGB(1, 1, 0, 0);
  VMC(4);  // A0,B0 resident; A1,B1 may fly
  BAR;

  bf16x8 afr[4][2], bfr0[2][2], bfr1[2][2];

  for (int t = 0; t < NT - 1; ++t) {
    const int buf = (t & 1) << 15;
    const int nb = buf ^ 32768;
    const int ko = (t + 1) * 64;
    // ph1: Q(0,0) — reads A0 (afr), B0 (bfr0); stage A0,B0(t+1)
    LDA(0, afr); LDB(0, bfr0);
    STGA(0, 0, nb, ko); STGA(0, 1, nb, ko);
    STGB(0, 0, nb, ko); STGB(0, 1, nb, ko);
    VMC(4);  // retires A1,B1(t); leaves A0,B0(t+1) in flight
    BAR;     // -> A1,B1(t) visible to all waves before ph2/ph3 reads
    MFMAQ(0, 0, afr, bfr0);
    // ph2: Q(0,1) — reads B1 (bfr1); afr kept; stage A1(t+1). no barrier.
    LDB(1, bfr1);
    STGA(1, 0, nb, ko); STGA(1, 1, nb, ko);
    MFMAQ(0, 1, afr, bfr1);
    // ph3: Q(1,1) — reads A1 (afr overwrite); bfr1 kept; stage B1(t+1).
    LDA(1, afr);
    STGB(1, 0, nb, ko); STGB(1, 1, nb, ko);
    MFMAQ(1, 1, afr, bfr1);
    // ph4: Q(1,0) — NO ds reads (afr=A1, bfr0=B0 both live)
    VMC(4);  // retires A0,B0(t+1); leaves A1,B1(t+1) in flight
    BAR;     // -> A0,B0(t+1) visible before next ph1 reads
    MFMAQ(1, 0, afr, bfr0);
  }
  {  // peeled last K-tile (t = NT-1, buf = 32768), no staging
    const int buf = 32768;
    LDA(0, afr); LDB(0, bfr0);
    VMC(0);  // drain: A1,B1 of last tile
    BAR;
    MFMAQ(0, 0, afr, bfr0);
    LDB(1, bfr1);
    MFMAQ(0, 1, afr, bfr1);
    LDA(1, afr);
    MFMAQ(1, 1, afr, bfr1);
    MFMAQ(1, 0, afr, bfr0);
  }

  // Epilogue: LDS-transpose (swizzled, stride 256) then coalesced 16B stores.
  // C/D layout: col=lane&15 (N), row=(lane>>4)*4+reg (M) [m89-verified].
  __syncthreads();
  const int rq = l4 * 4;
#pragma unroll
  for (int qm = 0; qm < 2; ++qm)
#pragma unroll
    for (int qn = 0; qn < 2; ++qn)
#pragma unroll
      for (int mi = 0; mi < 4; ++mi)
#pragma unroll
        for (int ni = 0; ni < 2; ++ni)
#pragma unroll
          for (int r = 0; r < 4; ++r) {
            int row = qm * 128 + wm * 64 + mi * 16 + rq + r;
            int col = (qn * 128 + wn * 32 + ni * 16 + c16) ^ ((row & 7) << 3);
            sm[row * 256 + col] = (bf16)acc[qm][qn][mi][ni][r];
          }
  __syncthreads();
#pragma unroll
  for (int p = 0; p < 16; ++p) {
    int row = p * 16 + (tid >> 5);
    int colL = (tid & 31) * 8;                    // logical col
    int col = colL ^ ((row & 7) << 3);            // swizzled LDS col
    bf16x8 v = *(const bf16x8*)(sm + row * 256 + col);
    *(bf16x8*)(C + (size_t)(mBase + row) * NN + nBase + colL) = v;
  }
#undef STGA
#undef STGB
#undef LDA
#undef LDB
#undef MFMAQ
#undef BAR
#undef VMC
}

// ========================== scan phases (shared) ===========================
// agg/pre layout: [chunk][channel] -> big-kernel access fully coalesced.

// phase 1: per-chunk aggregate (linear domain), 4 ch/thread, 2-row prefetch.
__device__ __forceinline__ void scan_phase1(const bf16* __restrict__ hW,
                                            float2* __restrict__ agg,
                                            int b, int c, int tid) {
  const int d0 = tid * 4;
  const bf16* p = hW + (size_t)(b * SS + c * CLEN) * NN + d0;
  float Fp[4] = {1.f, 1.f, 1.f, 1.f};
  float v[4] = {0.f, 0.f, 0.f, 0.f};
  bf16x4 hA = *(const bf16x4*)(p);
  bf16x4 fA = *(const bf16x4*)(p + DD);
  bf16x4 iA = *(const bf16x4*)(p + 2 * DD);
  const bf16* p1 = p + NN;
  bf16x4 hB = *(const bf16x4*)(p1);
  bf16x4 fB = *(const bf16x4*)(p1 + DD);
  bf16x4 iB = *(const bf16x4*)(p1 + 2 * DD);
  p += 2 * NN;
#pragma unroll 2
  for (int j = 0; j < CLEN - 2; ++j) {
    bf16x4 hn = *(const bf16x4*)(p);
    bf16x4 fn = *(const bf16x4*)(p + DD);
    bf16x4 in2 = *(const bf16x4*)(p + 2 * DD);
    p += NN;
#pragma unroll
    for (int e = 0; e < 4; ++e) {
      float F, IG;
      gate2((float)hA[e], (float)fA[e], (float)iA[e], F, IG);
      v[e] = fmaf(v[e], F, IG);
      Fp[e] *= F;
    }
    hA = hB; fA = fB; iA = iB;
    hB = hn; fB = fn; iB = in2;
  }
#pragma unroll
  for (int e = 0; e < 4; ++e) {  // row CLEN-2
    float F, IG;
    gate2((float)hA[e], (float)fA[e], (float)iA[e], F, IG);
    v[e] = fmaf(v[e], F, IG);
    Fp[e] *= F;
  }
#pragma unroll
  for (int e = 0; e < 4; ++e) {  // row CLEN-1
    float F, IG;
    gate2((float)hB[e], (float)fB[e], (float)iB[e], F, IG);
    v[e] = fmaf(v[e], F, IG);
    Fp[e] *= F;
  }
  float2* wout = agg + (size_t)c * NCH + b * DD + d0;
#pragma unroll
  for (int e = 0; e < 4; ++e)
    wout[e] =
        make_float2(__logf(fmaxf(Fp[e], 1e-37f)), __logf(fmaxf(v[e], 1e-37f)));
}

// phase 2: wave-parallel exclusive scan over chunks (log domain), 1 ch/wave.
__device__ __forceinline__ void scan_phase2(const float2* __restrict__ agg,
                                            float2* __restrict__ pre,
                                            int widx, int lane) {
  float2 vv[4];
#pragma unroll
  for (int q = 0; q < 4; ++q)
    vv[q] = aload(agg + (size_t)(lane * 4 + q) * NCH + widx);
  // lane-local fold
  float A = vv[0].x, V = vv[0].y;
#pragma unroll
  for (int q = 1; q < 4; ++q) comb(A, V, vv[q].x, vv[q].y);
  // inclusive wave scan of lane aggregates
#pragma unroll
  for (int off = 1; off < 64; off <<= 1) {
    float Ao = __shfl_up(A, off);
    float Vo = __shfl_up(V, off);
    if (lane >= off) {
      V = laddexp(Vo + A, V);
      A = Ao + A;
    }
  }
  // exclusive lane prefix
  float exA = __shfl_up(A, 1);
  float exV = __shfl_up(V, 1);
  if (lane == 0) { exA = 0.f; exV = -1e30f; }
  // emit exclusive per-chunk prefixes
#pragma unroll
  for (int q = 0; q < 4; ++q) {
    pre[(size_t)(lane * 4 + q) * NCH + widx] = make_float2(exA, exV);
    comb(exA, exV, vv[q].x, vv[q].y);
  }
}

// phase 3: re-run chunk in linear domain; out IS the state.
__device__ __forceinline__ void scan_phase3(const bf16* __restrict__ hW,
                                            const float2* __restrict__ pre,
                                            float* __restrict__ out,
                                            int b, int c, int tid) {
  const int d0 = tid * 4;
  const bf16* p = hW + (size_t)(b * SS + c * CLEN) * NN + d0;
  float* o = out + (size_t)(b * SS + c * CLEN) * DD + d0;
  const float2* pr = pre + (size_t)c * NCH + b * DD + d0;
  float v[4];
#pragma unroll
  for (int e = 0; e < 4; ++e)
    v[e] = __expf(aload(pr + e).y);  // exp(-1e30) = 0 for c=0
  bf16x4 hA = *(const bf16x4*)(p);
  bf16x4 fA = *(const bf16x4*)(p + DD);
  bf16x4 iA = *(const bf16x4*)(p + 2 * DD);
  const bf16* p1 = p + NN;
  bf16x4 hB = *(const bf16x4*)(p1);
  bf16x4 fB = *(const bf16x4*)(p1 + DD);
  bf16x4 iB = *(const bf16x4*)(p1 + 2 * DD);
  p += 2 * NN;
#pragma unroll 2
  for (int j = 0; j < CLEN - 2; ++j) {
    bf16x4 hn = *(const bf16x4*)(p);
    bf16x4 fn = *(const bf16x4*)(p + DD);
    bf16x4 in2 = *(const bf16x4*)(p + 2 * DD);
    p += NN;
    float4 ov;
#pragma unroll
    for (int e = 0; e < 4; ++e) {
      float F, IG;
      gate2((float)hA[e], (float)fA[e], (float)iA[e], F, IG);
      v[e] = fmaf(v[e], F, IG);
    }
    ov.x = v[0]; ov.y = v[1]; ov.z = v[2]; ov.w = v[3];
    *(float4*)o = ov;
    o += DD;
    hA = hB; fA = fB; iA = iB;
    hB = hn; fB = fn; iB = in2;
  }
  {  // row CLEN-2
    float4 ov;
#pragma unroll
    for (int e = 0; e < 4; ++e) {
      float F, IG;
      gate2((float)hA[e], (float)fA[e], (float)iA[e], F, IG);
      v[e] = fmaf(v[e], F, IG);
    }
    ov.x = v[0]; ov.y = v[1]; ov.z = v[2]; ov.w = v[3];
    *(float4*)o = ov;
    o += DD;
  }
  {  // row CLEN-1
    float4 ov;
#pragma unroll
    for (int e = 0; e < 4; ++e) {
      float F, IG;
      gate2((float)hB[e], (float)fB[e], (float)iB[e], F, IG);
      v[e] = fmaf(v[e], F, IG);
    }
    ov.x = v[0]; ov.y = v[1]; ov.z = v[2]; ov.w = v[3];
    *(float4*)o = ov;
  }
}

// ---- fused cooperative scan: phase1 -> sync -> phase2 -> sync -> phase3 ---
// 1024 blocks x 256 threads, min 4 waves/EU => 4 blocks/CU: all co-resident.
__global__ __launch_bounds__(256, 4) void k_scan_fused(
    const bf16* __restrict__ hW, float2* __restrict__ agg,
    float2* __restrict__ pre, float* __restrict__ out) {
  const int tid = threadIdx.x;
  const int b = blockIdx.y, c = blockIdx.z;
  cg::grid_group g = cg::this_grid();
  scan_phase1(hW, agg, b, c, tid);
  __threadfence();
  g.sync();
  scan_phase2(agg, pre, (c * BB + b) * 4 + (tid >> 6), tid & 63);
  __threadfence();
  g.sync();
  scan_phase3(hW, pre, out, b, c, tid);
}

// ---- fallback: same phases as 3 plain kernels -----------------------------
__global__ __launch_bounds__(256) void k_scan1(const bf16* __restrict__ hW,
                                               float2* __restrict__ agg) {
  scan_phase1(hW, agg, blockIdx.y, blockIdx.z, threadIdx.x);
}
__global__ __launch_bounds__(256) void k_scan2(const float2* __restrict__ agg,
                                               float2* __restrict__ pre) {
  scan_phase2(agg, pre, blockIdx.x * 4 + (threadIdx.x >> 6), threadIdx.x & 63);
}
__global__ __launch_bounds__(256) void k_scan3(const bf16* __restrict__ hW,
                                               const float2* __restrict__ pre,
                                               float* __restrict__ out) {
  scan_phase3(hW, pre, out, blockIdx.y, blockIdx.z, threadIdx.x);
}

extern "C" void kernel_launch(void* const* d_in, const int* in_sizes, int n_in,
                              void* d_out, int out_size, void* d_ws,
                              size_t ws_size, hipStream_t stream) {
  const float* x = (const float*)d_in[0];
  const float* W = (const float*)d_in[1];
  float* out = (float*)d_out;
  char* ws = (char*)d_ws;

  // workspace layout: [Wt 6MB][xb 64MB][hW 192MB]; agg/pre (8MB each) overlay
  // the xb region, which is dead after the GEMM completes.
  const size_t wtB = (size_t)NN * KK * 2;   //  6,291,456
  const size_t xbB = (size_t)MM * KK * 2;   // 67,108,864
  const size_t aggB = (size_t)CHUNKS * NCH * sizeof(float2);  // 8 MiB
  bf16* Wt = (bf16*)ws;
  bf16* xb = (bf16*)(ws + wtB);
  bf16* hW = (bf16*)(ws + wtB + xbB);
  float2* agg = (float2*)(ws + wtB);          // overlays xb (dead post-GEMM)
  float2* pre = (float2*)(ws + wtB + aggB);

  k_cvt_wt<<<dim3(NN / 32, KK / 32), dim3(32, 8), 0, stream>>>(W, Wt);
  k_cvt_x<<<dim3(MM * KK / 4 / 256), dim3(256), 0, stream>>>((const float4*)x,
                                                             (bf16x4*)xb);
  k_gemm<<<dim3((NN / 256) * (MM / 256)), 512, 0, stream>>>(xb, Wt, hW);

  {
    void* args[] = {(void*)&hW, (void*)&agg, (void*)&pre, (void*)&out};
    hipError_t e = hipLaunchCooperativeKernel(
        (void*)k_scan_fused, dim3(1, BB, CHUNKS), dim3(256, 1, 1), args, 0,
        stream);
    if (e != hipSuccess) {
      k_scan1<<<dim3(1, BB, CHUNKS), 256, 0, stream>>>(hW, agg);
      k_scan2<<<dim3(NCH / 4), 256, 0, stream>>>(agg, pre);
      k_scan3<<<dim3(1, BB, CHUNKS), 256, 0, stream>>>(hW, pre, out);
    }
  }
}

// Round 7
// 528.843 us; speedup vs baseline: 1.8679x; 1.8679x over previous
//
#include <hip/hip_runtime.h>
#include <hip/hip_bf16.h>
#include <cstdint>
#include <cstddef>

// minLSTM: out = exp(heinsen_scan(log_f, log_i + log_g(h))), [h,f,i] = x @ W
// B=4 S=8192 D=1024. GEMM bf16 MFMA (fp32 accum) -> bf16 hW; linear-domain
// chunked EMA scan (F=sigmoid(-d), I=1-F) with log-domain cross-chunk scan.
// R11: scans are LATENCY-bound (R10 fused-kernel counters: VALU 9%, HBM 9%,
// occ 47%). Fix: (a) CHUNKS 512 / CLEN 16, 2048 blocks @ launch_bounds(256,8)
// -> exactly 8 blocks/CU, one full round, 32 waves/CU; (b) explicit 4-deep
// static-slot prefetch rotation (12 loads in flight vs ~2); (c) keep R10's
// [chunk][channel] agg/pre layout (scan1/scan3 coalesced; strided access
// lives in L2-resident scan2). Cooperative fusion reverted (cost +250us).
// GEMM: R8 2-barrier schedule, unchanged (198us, MfmaUtil 47%).

#define BB 4
#define SS 8192
#define DD 1024
#define MM 32768   // B*S
#define KK 1024    // D
#define NN 3072    // 3*D
#define CHUNKS 512
#define CLEN 16    // SS / CHUNKS
#define NCH 4096   // B*D channels
#define NT 16      // KK / 64 K-tiles

typedef __bf16 bf16;
typedef __bf16 bf16x2 __attribute__((ext_vector_type(2)));
typedef __bf16 bf16x4 __attribute__((ext_vector_type(4)));
typedef __bf16 bf16x8 __attribute__((ext_vector_type(8)));
typedef float f32x4 __attribute__((ext_vector_type(4)));

// ---- async global->LDS, 16B per lane (wave-uniform LDS base + lane*16) ----
__device__ __forceinline__ void gload16(const bf16* g, bf16* l) {
  __builtin_amdgcn_global_load_lds(
      (const __attribute__((address_space(1))) unsigned int*)(const void*)g,
      (__attribute__((address_space(3))) unsigned int*)(void*)l,
      16, 0, 0);
}

// ---- native 2^x (hedged: fall back to __expf if builtin name is absent) ---
#if __has_builtin(__builtin_amdgcn_exp2f)
#define EXP2(x) __builtin_amdgcn_exp2f(x)
#else
#define EXP2(x) __expf((x) * 0.69314718056f)
#endif

// ---- linear-domain gate evaluation (base-2) -------------------------------
// F = sigmoid(-(sp(-f)-sp(-i))) = (1+e^-i)/(2+e^-f+e^-i); I = 1-F.
// IG = I * g(h), g(h) = h>=0 ? h+0.5 : sigmoid(h).
// Clamp exp2 args at 60: P<=2^60 keeps rZ normal; IG -> (P)(gh)(1/P) = gh ok.
__device__ __forceinline__ void gate2(float h, float f, float i,
                                      float& F, float& IG) {
  const float NL2E = -1.44269504089f;  // -log2(e)
  float P = EXP2(fminf(f * NL2E, 60.f));
  float Q = EXP2(fminf(i * NL2E, 60.f));
  float H = EXP2(fminf(h * NL2E, 60.f));
  float rZ = __builtin_amdgcn_rcpf(2.f + P + Q);
  float gh = (h >= 0.f) ? (h + 0.5f) : __builtin_amdgcn_rcpf(1.f + H);
  F = (1.f + Q) * rZ;
  IG = (1.f + P) * gh * rZ;
}

// ---- log-domain combine for the cross-chunk scan (scan2) ------------------
__device__ __forceinline__ float laddexp(float a, float b) {
  float m = fmaxf(a, b);
  return m + __logf(1.f + __expf(fminf(a, b) - m));
}
__device__ __forceinline__ void comb(float& A, float& V, float Ac, float Vc) {
  V = laddexp(V + Ac, Vc);
  A += Ac;
}

// ---- convert x fp32 -> bf16 (vectorized) ----
__global__ __launch_bounds__(256) void k_cvt_x(const float4* __restrict__ x,
                                               bf16x4* __restrict__ xb) {
  int i = blockIdx.x * 256 + threadIdx.x;
  float4 v = x[i];
  bf16x4 o;
  o[0] = (bf16)v.x; o[1] = (bf16)v.y; o[2] = (bf16)v.z; o[3] = (bf16)v.w;
  xb[i] = o;
}

// ---- convert + transpose W [K,N] fp32 -> Wt [N,K] bf16 (LDS 32x32 tile) ----
__global__ __launch_bounds__(256) void k_cvt_wt(const float* __restrict__ W,
                                                bf16* __restrict__ Wt) {
  __shared__ float tile[32][33];
  int n0 = blockIdx.x * 32, k0 = blockIdx.y * 32;
  int tx = threadIdx.x, ty = threadIdx.y;  // (32, 8)
#pragma unroll
  for (int i = 0; i < 32; i += 8)
    tile[ty + i][tx] = W[(size_t)(k0 + ty + i) * NN + n0 + tx];
  __syncthreads();
#pragma unroll
  for (int i = 0; i < 32; i += 8)
    Wt[(size_t)(n0 + ty + i) * KK + k0 + tx] = (bf16)tile[tx][ty + i];
}

// ---- bf16 GEMM, C[m][n] = sum_k A[m][k]*Bt[n][k] --------------------------
// 256x256 tile, BK=64, 8 waves (2Mx4N), counted vmcnt, LDS XOR-swizzle,
// dual B-frag sets, 2 barriers per K-tile. (R8, unchanged)
__global__ __launch_bounds__(512, 2) void k_gemm(const bf16* __restrict__ A,
                                                 const bf16* __restrict__ Bt,
                                                 bf16* __restrict__ C) {
  __shared__ __align__(16) bf16 sm[65536];  // 128 KiB
  const int tid = threadIdx.x;
  const int lane = tid & 63;
  const int w = tid >> 6;          // 0..7
  const int wm = w >> 2;           // 0..1 (M)
  const int wn = w & 3;            // 0..3 (N)
  const int c16 = lane & 15;
  const int l4 = lane >> 4;

  // XCD-aware bijective swizzle: 1536 blocks = 8 XCD * 192; nT fast inside
  // a chunk so consecutive same-XCD blocks reuse the A panel in L2.
  int bid = blockIdx.x;
  int swz = (bid & 7) * 192 + (bid >> 3);
  int mT = swz / 12;
  int nT = swz - mT * 12;
  const int mBase = mT * 256, nBase = nT * 256;

  // staging: thread covers LDS linear slot (row = tid>>3 (+64*L +128*half),
  // slot = tid&7); global source column pre-swizzled (inverse of read XOR).
  const int sr = tid >> 3;                       // 0..63
  const int scol = ((tid & 7) ^ (sr & 7)) * 8;   // swizzled k-col (elems)
  const bf16* gA = A + (size_t)(mBase + sr) * KK + scol;
  const bf16* gB = Bt + (size_t)(nBase + sr) * KK + scol;
  const int ld = tid * 8;                        // linear LDS dest (elems)

  // ds_read: addr = region + row*64 + ((slot ^ (row&7))*8); row&7 == c16&7
  const int sw8 = c16 & 7;
  const int sx0 = (l4 ^ sw8) * 8;          // ksub=0 (slots 0..3)
  const int sx1 = ((l4 + 4) ^ sw8) * 8;    // ksub=1 (slots 4..7)
  const int aRow = (wm * 64 + c16) * 64;   // + qm*8192 + mi*1024
  const int bRow = (wn * 32 + c16) * 64;   // + qn*8192 + ni*1024

  f32x4 acc[2][2][4][2];  // [qm][qn][mi][ni]
#pragma unroll
  for (int a = 0; a < 2; ++a)
#pragma unroll
    for (int b2 = 0; b2 < 2; ++b2)
#pragma unroll
      for (int m = 0; m < 4; ++m)
#pragma unroll
        for (int n = 0; n < 2; ++n)
          acc[a][b2][m][n] = (f32x4){0.f, 0.f, 0.f, 0.f};

#define STGA(h, L, bo, ko) \
  gload16(gA + (h) * 131072 + (L) * 65536 + (ko), \
          sm + (bo) + (h) * 8192 + (L) * 4096 + ld)
#define STGB(h, L, bo, ko) \
  gload16(gB + (h) * 131072 + (L) * 65536 + (ko), \
          sm + (bo) + 16384 + (h) * 8192 + (L) * 4096 + ld)
#define LDA(qm, AF)                                                     \
  _Pragma("unroll") for (int mi = 0; mi < 4; ++mi) {                    \
    const bf16* p_ = sm + buf + (qm) * 8192 + aRow + mi * 1024;         \
    AF[mi][0] = *(const bf16x8*)(p_ + sx0);                             \
    AF[mi][1] = *(const bf16x8*)(p_ + sx1);                             \
  }
#define LDB(qn, BF)                                                     \
  _Pragma("unroll") for (int ni = 0; ni < 2; ++ni) {                    \
    const bf16* p_ = sm + buf + 16384 + (qn) * 8192 + bRow + ni * 1024; \
    BF[ni][0] = *(const bf16x8*)(p_ + sx0);                             \
    BF[ni][1] = *(const bf16x8*)(p_ + sx1);                             \
  }
#define MFMAQ(qm, qn, AF, BF)                                             \
  __builtin_amdgcn_s_setprio(1);                                          \
  _Pragma("unroll") for (int mi = 0; mi < 4; ++mi)                        \
  _Pragma("unroll") for (int ni = 0; ni < 2; ++ni) {                      \
    acc[qm][qn][mi][ni] = __builtin_amdgcn_mfma_f32_16x16x32_bf16(        \
        AF[mi][0], BF[ni][0], acc[qm][qn][mi][ni], 0, 0, 0);              \
    acc[qm][qn][mi][ni] = __builtin_amdgcn_mfma_f32_16x16x32_bf16(        \
        AF[mi][1], BF[ni][1], acc[qm][qn][mi][ni], 0, 0, 0);              \
  }                                                                       \
  __builtin_amdgcn_s_setprio(0);
#define BAR asm volatile("s_barrier" ::: "memory")
#define VMC(n) asm volatile("s_waitcnt vmcnt(" #n ")" ::: "memory")

  // prologue: stage K-tile 0 into buffer 0 (issue order A0,B0,A1,B1)
  STGA(0, 0, 0, 0); STGA(0, 1, 0, 0); STGB(0, 0, 0, 0); STGB(0, 1, 0, 0);
  STGA(1, 0, 0, 0); STGA(1, 1, 0, 0); STGB(1, 0, 0, 0); STGB(1, 1, 0, 0);
  VMC(4);  // A0,B0 resident; A1,B1 may fly
  BAR;

  bf16x8 afr[4][2], bfr0[2][2], bfr1[2][2];

  for (int t = 0; t < NT - 1; ++t) {
    const int buf = (t & 1) << 15;
    const int nb = buf ^ 32768;
    const int ko = (t + 1) * 64;
    // ph1: Q(0,0) — reads A0 (afr), B0 (bfr0); stage A0,B0(t+1)
    LDA(0, afr); LDB(0, bfr0);
    STGA(0, 0, nb, ko); STGA(0, 1, nb, ko);
    STGB(0, 0, nb, ko); STGB(0, 1, nb, ko);
    VMC(4);  // retires A1,B1(t); leaves A0,B0(t+1) in flight
    BAR;     // -> A1,B1(t) visible to all waves before ph2/ph3 reads
    MFMAQ(0, 0, afr, bfr0);
    // ph2: Q(0,1) — reads B1 (bfr1); afr kept; stage A1(t+1). no barrier.
    LDB(1, bfr1);
    STGA(1, 0, nb, ko); STGA(1, 1, nb, ko);
    MFMAQ(0, 1, afr, bfr1);
    // ph3: Q(1,1) — reads A1 (afr overwrite); bfr1 kept; stage B1(t+1).
    LDA(1, afr);
    STGB(1, 0, nb, ko); STGB(1, 1, nb, ko);
    MFMAQ(1, 1, afr, bfr1);
    // ph4: Q(1,0) — NO ds reads (afr=A1, bfr0=B0 both live)
    VMC(4);  // retires A0,B0(t+1); leaves A1,B1(t+1) in flight
    BAR;     // -> A0,B0(t+1) visible before next ph1 reads
    MFMAQ(1, 0, afr, bfr0);
  }
  {  // peeled last K-tile (t = NT-1, buf = 32768), no staging
    const int buf = 32768;
    LDA(0, afr); LDB(0, bfr0);
    VMC(0);  // drain: A1,B1 of last tile
    BAR;
    MFMAQ(0, 0, afr, bfr0);
    LDB(1, bfr1);
    MFMAQ(0, 1, afr, bfr1);
    LDA(1, afr);
    MFMAQ(1, 1, afr, bfr1);
    MFMAQ(1, 0, afr, bfr0);
  }

  // Epilogue: LDS-transpose (swizzled, stride 256) then coalesced 16B stores.
  // C/D layout: col=lane&15 (N), row=(lane>>4)*4+reg (M) [m89-verified].
  __syncthreads();
  const int rq = l4 * 4;
#pragma unroll
  for (int qm = 0; qm < 2; ++qm)
#pragma unroll
    for (int qn = 0; qn < 2; ++qn)
#pragma unroll
      for (int mi = 0; mi < 4; ++mi)
#pragma unroll
        for (int ni = 0; ni < 2; ++ni)
#pragma unroll
          for (int r = 0; r < 4; ++r) {
            int row = qm * 128 + wm * 64 + mi * 16 + rq + r;
            int col = (qn * 128 + wn * 32 + ni * 16 + c16) ^ ((row & 7) << 3);
            sm[row * 256 + col] = (bf16)acc[qm][qn][mi][ni][r];
          }
  __syncthreads();
#pragma unroll
  for (int p = 0; p < 16; ++p) {
    int row = p * 16 + (tid >> 5);
    int colL = (tid & 31) * 8;                    // logical col
    int col = colL ^ ((row & 7) << 3);            // swizzled LDS col
    bf16x8 v = *(const bf16x8*)(sm + row * 256 + col);
    *(bf16x8*)(C + (size_t)(mBase + row) * NN + nBase + colL) = v;
  }
#undef STGA
#undef STGB
#undef LDA
#undef LDB
#undef MFMAQ
#undef BAR
#undef VMC
}

// ========================== scan kernels ===================================
// agg/pre layout: [chunk][channel] -> scan1 writes / scan3 reads coalesced.
// 4-deep static-slot prefetch rotation (rule #20: no runtime reg indexing).

#define LDROW(s, pp)                      \
  h##s = *(const bf16x4*)(pp);            \
  f##s = *(const bf16x4*)((pp) + DD);     \
  i##s = *(const bf16x4*)((pp) + 2 * DD)

// ---- scan phase 1: per-chunk aggregate (linear), 4 ch/thread --------------
__global__ __launch_bounds__(256, 8) void k_scan1(const bf16* __restrict__ hW,
                                                  float2* __restrict__ agg) {
  const int d0 = threadIdx.x * 4;
  const int b = blockIdx.y, c = blockIdx.z;
  const bf16* p = hW + (size_t)(b * SS + c * CLEN) * NN + d0;
  float Fp[4] = {1.f, 1.f, 1.f, 1.f};
  float v[4] = {0.f, 0.f, 0.f, 0.f};
  bf16x4 h0, f0, i0, h1, f1, i1, h2, f2, i2, h3, f3, i3;
  LDROW(0, p); LDROW(1, p + NN); LDROW(2, p + 2 * NN); LDROW(3, p + 3 * NN);
  const bf16* q = p + 4 * NN;
#define C1(s)                                                         \
  do {                                                                \
    _Pragma("unroll") for (int e = 0; e < 4; ++e) {                   \
      float F, IG;                                                    \
      gate2((float)h##s[e], (float)f##s[e], (float)i##s[e], F, IG);   \
      v[e] = fmaf(v[e], F, IG);                                       \
      Fp[e] *= F;                                                     \
    }                                                                 \
  } while (0)
  C1(0); LDROW(0, q); q += NN;   // j=0,  load row 4
  C1(1); LDROW(1, q); q += NN;   // j=1,  row 5
  C1(2); LDROW(2, q); q += NN;   // j=2,  row 6
  C1(3); LDROW(3, q); q += NN;   // j=3,  row 7
  C1(0); LDROW(0, q); q += NN;   // j=4,  row 8
  C1(1); LDROW(1, q); q += NN;   // j=5,  row 9
  C1(2); LDROW(2, q); q += NN;   // j=6,  row 10
  C1(3); LDROW(3, q); q += NN;   // j=7,  row 11
  C1(0); LDROW(0, q); q += NN;   // j=8,  row 12
  C1(1); LDROW(1, q); q += NN;   // j=9,  row 13
  C1(2); LDROW(2, q); q += NN;   // j=10, row 14
  C1(3); LDROW(3, q);            // j=11, row 15
  C1(0); C1(1); C1(2); C1(3);    // j=12..15
#undef C1
  float2* wout = agg + (size_t)c * NCH + b * DD + d0;
#pragma unroll
  for (int e = 0; e < 4; ++e)
    wout[e] =
        make_float2(__logf(fmaxf(Fp[e], 1e-37f)), __logf(fmaxf(v[e], 1e-37f)));
}

// ---- scan phase 2: wave-parallel exclusive scan over chunks (log domain) --
// One wave per channel; lane holds 8 chunk aggregates; shfl tree scan.
// Strided [chunk][ch] access (32KB stride) is L2/L3-resident (16MB).
__global__ __launch_bounds__(256) void k_scan2(const float2* __restrict__ agg,
                                               float2* __restrict__ pre) {
  const int ch = blockIdx.x * 4 + (threadIdx.x >> 6);
  const int lane = threadIdx.x & 63;
  float2 vv[8];
#pragma unroll
  for (int q = 0; q < 8; ++q)
    vv[q] = agg[(size_t)(lane * 8 + q) * NCH + ch];
  // lane-local fold (8 chunks)
  float A = vv[0].x, V = vv[0].y;
#pragma unroll
  for (int q = 1; q < 8; ++q) comb(A, V, vv[q].x, vv[q].y);
  // inclusive wave scan of lane aggregates
#pragma unroll
  for (int off = 1; off < 64; off <<= 1) {
    float Ao = __shfl_up(A, off);
    float Vo = __shfl_up(V, off);
    if (lane >= off) {
      V = laddexp(Vo + A, V);
      A = Ao + A;
    }
  }
  // exclusive lane prefix
  float exA = __shfl_up(A, 1);
  float exV = __shfl_up(V, 1);
  if (lane == 0) { exA = 0.f; exV = -1e30f; }
  // emit exclusive per-chunk prefixes
#pragma unroll
  for (int q = 0; q < 8; ++q) {
    pre[(size_t)(lane * 8 + q) * NCH + ch] = make_float2(exA, exV);
    comb(exA, exV, vv[q].x, vv[q].y);
  }
}

// ---- scan phase 3: re-run chunk in linear domain; out IS the state --------
__global__ __launch_bounds__(256, 8) void k_scan3(const bf16* __restrict__ hW,
                                                  const float2* __restrict__ pre,
                                                  float* __restrict__ out) {
  const int d0 = threadIdx.x * 4;
  const int b = blockIdx.y, c = blockIdx.z;
  const bf16* p = hW + (size_t)(b * SS + c * CLEN) * NN + d0;
  float* o = out + (size_t)(b * SS + c * CLEN) * DD + d0;
  const float2* pr = pre + (size_t)c * NCH + b * DD + d0;
  float v[4];
#pragma unroll
  for (int e = 0; e < 4; ++e)
    v[e] = __expf(pr[e].y);  // exp(-1e30) = 0 for c=0
  bf16x4 h0, f0, i0, h1, f1, i1, h2, f2, i2, h3, f3, i3;
  LDROW(0, p); LDROW(1, p + NN); LDROW(2, p + 2 * NN); LDROW(3, p + 3 * NN);
  const bf16* q = p + 4 * NN;
#define C3(s)                                                         \
  do {                                                                \
    float4 ov;                                                        \
    _Pragma("unroll") for (int e = 0; e < 4; ++e) {                   \
      float F, IG;                                                    \
      gate2((float)h##s[e], (float)f##s[e], (float)i##s[e], F, IG);   \
      v[e] = fmaf(v[e], F, IG);                                       \
    }                                                                 \
    ov.x = v[0]; ov.y = v[1]; ov.z = v[2]; ov.w = v[3];               \
    *(float4*)o = ov;                                                 \
    o += DD;                                                          \
  } while (0)
  C3(0); LDROW(0, q); q += NN;   // j=0,  load row 4
  C3(1); LDROW(1, q); q += NN;
  C3(2); LDROW(2, q); q += NN;
  C3(3); LDROW(3, q); q += NN;
  C3(0); LDROW(0, q); q += NN;
  C3(1); LDROW(1, q); q += NN;
  C3(2); LDROW(2, q); q += NN;
  C3(3); LDROW(3, q); q += NN;
  C3(0); LDROW(0, q); q += NN;
  C3(1); LDROW(1, q); q += NN;
  C3(2); LDROW(2, q); q += NN;
  C3(3); LDROW(3, q);            // row 15
  C3(0); C3(1); C3(2); C3(3);    // j=12..15
#undef C3
}

extern "C" void kernel_launch(void* const* d_in, const int* in_sizes, int n_in,
                              void* d_out, int out_size, void* d_ws,
                              size_t ws_size, hipStream_t stream) {
  const float* x = (const float*)d_in[0];
  const float* W = (const float*)d_in[1];
  float* out = (float*)d_out;
  char* ws = (char*)d_ws;

  // workspace layout: [Wt 6MB][xb 64MB][hW 192MB]; agg/pre (16MB each)
  // overlay the xb region, which is dead after the GEMM completes.
  const size_t wtB = (size_t)NN * KK * 2;   //  6,291,456
  const size_t xbB = (size_t)MM * KK * 2;   // 67,108,864
  const size_t aggB = (size_t)CHUNKS * NCH * sizeof(float2);  // 16 MiB
  bf16* Wt = (bf16*)ws;
  bf16* xb = (bf16*)(ws + wtB);
  bf16* hW = (bf16*)(ws + wtB + xbB);
  float2* agg = (float2*)(ws + wtB);          // overlays xb (dead post-GEMM)
  float2* pre = (float2*)(ws + wtB + aggB);

  k_cvt_wt<<<dim3(NN / 32, KK / 32), dim3(32, 8), 0, stream>>>(W, Wt);
  k_cvt_x<<<dim3(MM * KK / 4 / 256), dim3(256), 0, stream>>>((const float4*)x,
                                                             (bf16x4*)xb);
  k_gemm<<<dim3((NN / 256) * (MM / 256)), 512, 0, stream>>>(xb, Wt, hW);
  k_scan1<<<dim3(1, BB, CHUNKS), 256, 0, stream>>>(hW, agg);
  k_scan2<<<dim3(NCH / 4), 256, 0, stream>>>(agg, pre);
  k_scan3<<<dim3(1, BB, CHUNKS), 256, 0, stream>>>(hW, pre, out);
}